// Round 2
// baseline (663.175 us; speedup 1.0000x reference)
//
#include <hip/hip_runtime.h>
#include <stdint.h>

#define B_ 4
#define S_ 4096
#define D_ 1024
#define HALF_ 64

typedef __attribute__((ext_vector_type(4))) float f32x4;
typedef __attribute__((ext_vector_type(8))) short short8;
typedef __attribute__((ext_vector_type(4))) short short4v;
typedef __attribute__((ext_vector_type(4))) float float4v;

__device__ __forceinline__ short f2bf(float f) {
  union { float f; uint32_t u; } x;
  x.f = f;
  uint32_t u = x.u;
  uint32_t r = (u + 0x7FFFu + ((u >> 16) & 1u)) >> 16;
  return (short)(r & 0xFFFFu);
}

__device__ __forceinline__ void gload_lds16(const void* g, void* l) {
  __builtin_amdgcn_global_load_lds(
      (const __attribute__((address_space(1))) void*)g,
      (__attribute__((address_space(3))) void*)l, 16, 0, 0);
}

// ---------------- cast f32 -> bf16 (vectorized, grid-stride) ----------------
__global__ __launch_bounds__(256) void cast_f32_to_bf16(
    const float* __restrict__ in, short* __restrict__ out, int n4) {
  int stride = gridDim.x * blockDim.x;
  for (int i = blockIdx.x * blockDim.x + threadIdx.x; i < n4; i += stride) {
    float4v v = *(const float4v*)(in + (size_t)i * 4);
    short4v o;
    o.x = f2bf(v.x);
    o.y = f2bf(v.y);
    o.z = f2bf(v.z);
    o.w = f2bf(v.w);
    *(short4v*)(out + (size_t)i * 4) = o;
  }
}

// ---------------- GEMM: C[m,n] = sum_k A[m,k]*Bw[n,k] + bias[n] ----------------
// A:[M,K] bf16 row-major, Bw:[N,K] bf16 row-major, C:[M,N] bf16.
// 128x128 tile, BK=64, 4 waves (2x2), each wave 64x64 (4x4 MFMA frags).
__global__ __launch_bounds__(256) void gemm_bias_bf16(
    const short* __restrict__ A, const short* __restrict__ Bw,
    const float* __restrict__ bias, short* __restrict__ C,
    int M, int N, int K) {
  __shared__ __align__(16) short Asm[128 * 64];
  __shared__ __align__(16) short Bsm[128 * 64];
  const int tid = threadIdx.x;
  const int l = tid & 63;
  const int w = tid >> 6;
  const int nt = N >> 7;
  const int m0 = (blockIdx.x / nt) << 7;
  const int n0 = (blockIdx.x % nt) << 7;
  const int wr = w >> 1, wc = w & 1;

  f32x4 acc[4][4];
#pragma unroll
  for (int i = 0; i < 4; ++i)
#pragma unroll
    for (int j = 0; j < 4; ++j) acc[i][j] = (f32x4){0.f, 0.f, 0.f, 0.f};

  int srow[4], scol[4], slds[4];
#pragma unroll
  for (int r = 0; r < 4; ++r) {
    int q = r * 4096 + w * 1024 + l * 16;  // byte offset within 16KB tile
    srow[r] = q >> 7;                      // tile row (128B rows)
    scol[r] = (q & 127) >> 1;              // element offset in row
    slds[r] = (r * 4096 + w * 1024) >> 1;  // wave-uniform LDS element base
  }

  const int kiters = K >> 6;
  for (int kt = 0; kt < kiters; ++kt) {
    const int kb = kt << 6;
#pragma unroll
    for (int r = 0; r < 4; ++r) {
      gload_lds16(A + (size_t)(m0 + srow[r]) * K + kb + scol[r], &Asm[slds[r]]);
      gload_lds16(Bw + (size_t)(n0 + srow[r]) * K + kb + scol[r], &Bsm[slds[r]]);
    }
    __syncthreads();
#pragma unroll
    for (int ks = 0; ks < 2; ++ks) {
      short8 af[4], bf[4];
#pragma unroll
      for (int mi = 0; mi < 4; ++mi)
        af[mi] = *(const short8*)&Asm[((wr << 6) + (mi << 4) + (l & 15)) * 64 +
                                      (ks << 5) + ((l >> 4) << 3)];
#pragma unroll
      for (int ni = 0; ni < 4; ++ni)
        bf[ni] = *(const short8*)&Bsm[((wc << 6) + (ni << 4) + (l & 15)) * 64 +
                                      (ks << 5) + ((l >> 4) << 3)];
#pragma unroll
      for (int mi = 0; mi < 4; ++mi)
#pragma unroll
        for (int ni = 0; ni < 4; ++ni)
          acc[mi][ni] = __builtin_amdgcn_mfma_f32_16x16x32_bf16(
              af[mi], bf[ni], acc[mi][ni], 0, 0, 0);
    }
    __syncthreads();
  }

#pragma unroll
  for (int ni = 0; ni < 4; ++ni) {
    const int col = n0 + (wc << 6) + (ni << 4) + (l & 15);
    const float bv = bias[col];
#pragma unroll
    for (int mi = 0; mi < 4; ++mi) {
      const int row = m0 + (wr << 6) + (mi << 4) + ((l >> 4) << 2);
#pragma unroll
      for (int r = 0; r < 4; ++r)
        C[(size_t)(row + r) * N + col] = f2bf(acc[mi][ni][r] + bv);
    }
  }
}

// ---------------- transpose V [B*S, D] -> Vt [B, D, S] ----------------
__global__ __launch_bounds__(256) void transpose_bf16(
    const short* __restrict__ V, short* __restrict__ Vt) {
  __shared__ __align__(16) short t[64][72];
  const int i0 = blockIdx.x << 6;
  const int d0 = blockIdx.y << 6;
  const int b = blockIdx.z;
  const int tid = threadIdx.x;
  const int lr = tid >> 3;        // 0..31
  const int lc = (tid & 7) << 3;  // 0,8,...,56
#pragma unroll
  for (int rr = 0; rr < 2; ++rr) {
    int row = (rr << 5) + lr;
    short8 v = *(const short8*)&V[((size_t)b * S_ + i0 + row) * D_ + d0 + lc];
    *(short8*)&t[row][lc] = v;
  }
  __syncthreads();
#pragma unroll
  for (int rr = 0; rr < 2; ++rr) {
    int drow = (rr << 5) + lr;
    short8 v;
#pragma unroll
    for (int q = 0; q < 8; ++q) v[q] = t[lc + q][drow];
    *(short8*)&Vt[((size_t)b * D_ + d0 + drow) * S_ + i0 + lc] = v;
  }
}

// ---------------- fused sliding-window attention ----------------
// Per block: 64 Q rows (one b), band of 192 K/V rows [i0-64, i0+127].
// 4 waves, wave w owns rows iw..iw+15. MFMA 16x16x32 bf16.
__global__ __launch_bounds__(256, 1) void swa_fused(
    const short* __restrict__ Qb, const short* __restrict__ Kb,
    const short* __restrict__ Vtb, float* __restrict__ outO,
    float* __restrict__ outW) {
  __shared__ __align__(16) short P_lds[4][16][200];
  const int tid = threadIdx.x;
  const int l = tid & 63;
  const int w = tid >> 6;
  const int b = blockIdx.y;
  const int i0 = blockIdx.x << 6;
  const int iw = i0 + (w << 4);
  const int j0 = i0 - 64;
  const int lq = l & 15;  // C-layout col / A-row
  const int lg = l >> 4;  // k-group

  // ---- Phase A: scores band S[64,192] = Q K^T ----
  f32x4 acc[12];
#pragma unroll
  for (int jc = 0; jc < 12; ++jc) acc[jc] = (f32x4){0.f, 0.f, 0.f, 0.f};

  const short* qptr = Qb + ((size_t)b * S_ + iw + lq) * D_ + (lg << 3);
  const short* kptr[12];
#pragma unroll
  for (int jc = 0; jc < 12; ++jc) {
    int j = j0 + (jc << 4) + lq;
    int jcl = j < 0 ? 0 : (j > S_ - 1 ? S_ - 1 : j);
    kptr[jc] = Kb + ((size_t)b * S_ + jcl) * D_ + (lg << 3);
  }
#pragma unroll 2
  for (int d0 = 0; d0 < D_; d0 += 32) {
    short8 qa = *(const short8*)(qptr + d0);
#pragma unroll
    for (int jc = 0; jc < 12; ++jc) {
      short8 kv = *(const short8*)(kptr[jc] + d0);
      acc[jc] = __builtin_amdgcn_mfma_f32_16x16x32_bf16(qa, kv, acc[jc], 0, 0, 0);
    }
  }

  // ---- Phase B: softmax over band (rows split by C-layout), write weights ----
  const float scale = 0.03125f;  // 1/sqrt(1024)
#pragma unroll
  for (int r = 0; r < 4; ++r) {
    const int i = iw + (lg << 2) + r;
    float sv[12];
    float m = -3.0e38f;
#pragma unroll
    for (int jc = 0; jc < 12; ++jc) {
      int j = j0 + (jc << 4) + lq;
      bool valid = (j >= i - HALF_) && (j <= i + HALF_) && (j >= 0) && (j < S_);
      float s = acc[jc][r] * scale;
      sv[jc] = valid ? s : -3.0e38f;
      m = fmaxf(m, sv[jc]);
    }
#pragma unroll
    for (int mk = 1; mk <= 8; mk <<= 1) m = fmaxf(m, __shfl_xor(m, mk, 64));
    float p[12];
    float sum = 0.f;
#pragma unroll
    for (int jc = 0; jc < 12; ++jc) {
      p[jc] = (sv[jc] > -1.0e38f) ? __expf(sv[jc] - m) : 0.f;
      sum += p[jc];
    }
#pragma unroll
    for (int mk = 1; mk <= 8; mk <<= 1) sum += __shfl_xor(sum, mk, 64);
    const float inv = 1.0f / sum;
    float* wrow = outW + ((size_t)b * S_ + i) * S_;
#pragma unroll
    for (int jc = 0; jc < 12; ++jc) {
      int j = j0 + (jc << 4) + lq;
      float pw = p[jc] * inv;
      if (j >= 0 && j < S_) wrow[j] = pw;
      P_lds[w][(lg << 2) + r][(jc << 4) + lq] = f2bf(pw);
    }
  }

  __syncthreads();

  // ---- Phase C: O[64,1024] = P[64,192] @ V_band ----
  short8 pa[6];
#pragma unroll
  for (int ks = 0; ks < 6; ++ks)
    pa[ks] = *(const short8*)&P_lds[w][lq][(ks << 5) + (lg << 3)];

  const short* vbase = Vtb + ((size_t)b * D_ + lq) * S_;
  int joff[6];
#pragma unroll
  for (int ks = 0; ks < 6; ++ks) {
    int j = j0 + (ks << 5) + (lg << 3);
    joff[ks] = j < 0 ? 0 : (j > S_ - 8 ? S_ - 8 : j);
  }
  float* obase = outO + ((size_t)b * S_ + iw + (lg << 2)) * D_ + lq;
#pragma unroll 2
  for (int dc = 0; dc < 64; ++dc) {
    f32x4 o = (f32x4){0.f, 0.f, 0.f, 0.f};
    const short* vd = vbase + ((size_t)(dc << 4)) * S_;
#pragma unroll
    for (int ks = 0; ks < 6; ++ks) {
      short8 vv = *(const short8*)(vd + joff[ks]);
      o = __builtin_amdgcn_mfma_f32_16x16x32_bf16(pa[ks], vv, o, 0, 0, 0);
    }
#pragma unroll
    for (int r = 0; r < 4; ++r) obase[(size_t)r * D_ + (dc << 4)] = o[r];
  }
}

// ---------------- launch ----------------
extern "C" void kernel_launch(void* const* d_in, const int* in_sizes, int n_in,
                              void* d_out, int out_size, void* d_ws, size_t ws_size,
                              hipStream_t stream) {
  (void)in_sizes; (void)n_in; (void)out_size; (void)ws_size;
  const float* x  = (const float*)d_in[0];
  const float* Wq = (const float*)d_in[1];
  const float* bq = (const float*)d_in[2];
  const float* Wk = (const float*)d_in[3];
  const float* bk = (const float*)d_in[4];
  const float* Wv = (const float*)d_in[5];
  const float* bv = (const float*)d_in[6];

  const size_t NX = (size_t)B_ * S_ * D_;      // 16,777,216
  const size_t NW = (size_t)D_ * D_;           // 1,048,576

  char* ws = (char*)d_ws;
  size_t off = 0;
  short* xb  = (short*)(ws + off); off += NX * 2;
  short* Wqb = (short*)(ws + off); off += NW * 2;
  short* Wkb = (short*)(ws + off); off += NW * 2;
  short* Wvb = (short*)(ws + off); off += NW * 2;
  short* Qb  = (short*)(ws + off); off += NX * 2;
  short* Kb  = (short*)(ws + off); off += NX * 2;
  short* Vb  = (short*)(ws + off); off += NX * 2;
  short* Vtb = (short*)(ws + off); off += NX * 2;

  float* outO = (float*)d_out;
  float* outW = outO + NX;

  // zero the full [B,S,S] attn-weights buffer (out-of-band entries are 0)
  hipMemsetAsync(outW, 0, (size_t)B_ * S_ * S_ * sizeof(float), stream);

  // casts
  cast_f32_to_bf16<<<4096, 256, 0, stream>>>(x, xb, (int)(NX / 4));
  cast_f32_to_bf16<<<1024, 256, 0, stream>>>(Wq, Wqb, (int)(NW / 4));
  cast_f32_to_bf16<<<1024, 256, 0, stream>>>(Wk, Wkb, (int)(NW / 4));
  cast_f32_to_bf16<<<1024, 256, 0, stream>>>(Wv, Wvb, (int)(NW / 4));

  // projections: [16384,1024] x [1024,1024]^T + bias
  const int M = B_ * S_, N = D_, K = D_;
  dim3 ggrid((M / 128) * (N / 128));
  gemm_bias_bf16<<<ggrid, 256, 0, stream>>>(xb, Wqb, bq, Qb, M, N, K);
  gemm_bias_bf16<<<ggrid, 256, 0, stream>>>(xb, Wkb, bk, Kb, M, N, K);
  gemm_bias_bf16<<<ggrid, 256, 0, stream>>>(xb, Wvb, bv, Vb, M, N, K);

  // V -> Vt [B, D, S]
  transpose_bf16<<<dim3(S_ / 64, D_ / 64, B_), 256, 0, stream>>>(Vb, Vtb);

  // fused band attention
  swa_fused<<<dim3(S_ / 64, B_), 256, 0, stream>>>(Qb, Kb, Vtb, outO, outW);
}